// Round 2
// baseline (1497.520 us; speedup 1.0000x reference)
//
#include <hip/hip_runtime.h>

#define NN 100000
#define NE 1600000
#define DIM 128
#define NA 5
#define STEPS 5
#define ODE_NB 48

typedef float vf2 __attribute__((ext_vector_type(2)));

__device__ __forceinline__ float wsum(float v) {
#pragma unroll
  for (int off = 32; off > 0; off >>= 1) v += __shfl_xor(v, off, 64);
  return v;
}

// ---- prep: transpose W1a, W2; M = edge_anchor @ W1b.T ----
__global__ __launch_bounds__(128) void k_prep(
    const float* __restrict__ W1, const float* __restrict__ W2,
    const float* __restrict__ edge_anchor,
    float* __restrict__ W1aT, float* __restrict__ W2T, float* __restrict__ M) {
  const int i = threadIdx.x;
  const int b = blockIdx.x;
  if (b < DIM) {
    W1aT[b * DIM + i] = W1[i * 2 * DIM + b];
    W2T[b * DIM + i] = W2[i * DIM + b];
  } else {
    const int a = b - DIM;
    float s = 0.f;
    for (int j = 0; j < DIM; ++j)
      s = fmaf(edge_anchor[a * DIM + j], W1[i * 2 * DIM + DIM + j], s);
    M[a * DIM + i] = s;
  }
}

// ---- node pre-pass: att softmax + node_x, and p1/p2 edge projections ----
__global__ __launch_bounds__(256) void k_node(
    const float* __restrict__ x, const float* __restrict__ W_att,
    const float* __restrict__ b_att, const float* __restrict__ node_anchor,
    const float* __restrict__ W_edge, const float* __restrict__ b_edge,
    float* __restrict__ node_x, float* __restrict__ p12) {
  const int wid = threadIdx.x >> 6, lane = threadIdx.x & 63;
  const int d0 = lane << 1;
  float wa0[NA], wa1[NA], we10[NA], we11[NA], we20[NA], we21[NA];
  float na0[NA], na1[NA], ba[NA], be[NA];
#pragma unroll
  for (int a = 0; a < NA; ++a) {
    wa0[a] = W_att[a * DIM + d0];
    wa1[a] = W_att[a * DIM + d0 + 1];
    we10[a] = W_edge[a * 2 * DIM + d0];
    we11[a] = W_edge[a * 2 * DIM + d0 + 1];
    we20[a] = W_edge[a * 2 * DIM + DIM + d0];
    we21[a] = W_edge[a * 2 * DIM + DIM + d0 + 1];
    na0[a] = node_anchor[a * DIM + d0];
    na1[a] = node_anchor[a * DIM + d0 + 1];
    ba[a] = b_att[a];
    be[a] = b_edge[a];
  }
  const int stride = gridDim.x << 2;
  for (int n = (blockIdx.x << 2) + wid; n < NN; n += stride) {
    float2 xv = *(const float2*)(x + (size_t)n * DIM + d0);
    float att[NA], p1[NA], p2[NA];
#pragma unroll
    for (int a = 0; a < NA; ++a) {
      att[a] = wsum(xv.x * wa0[a] + xv.y * wa1[a]) + ba[a];
      p1[a] = wsum(xv.x * we10[a] + xv.y * we11[a]) + be[a];  // fold b_edge
      p2[a] = wsum(xv.x * we20[a] + xv.y * we21[a]);
    }
    float m = fmaxf(fmaxf(fmaxf(att[0], att[1]), fmaxf(att[2], att[3])), att[4]);
    float s = 0.f;
#pragma unroll
    for (int a = 0; a < NA; ++a) { att[a] = expf(att[a] - m); s += att[a]; }
    float inv = 1.f / s;
    float2 nx = xv;
#pragma unroll
    for (int a = 0; a < NA; ++a) {
      float w = att[a] * inv;
      nx.x = fmaf(w, na0[a], nx.x);
      nx.y = fmaf(w, na1[a], nx.y);
    }
    *(float2*)(node_x + (size_t)n * DIM + d0) = nx;
    if (lane < NA) {
      float v1 = p1[0], v2 = p2[0];
#pragma unroll
      for (int a = 1; a < NA; ++a)
        if (lane == a) { v1 = p1[a]; v2 = p2[a]; }
      p12[(size_t)n * 16 + lane] = v1;
      p12[(size_t)n * 16 + 8 + lane] = v2;
    }
  }
}

// ---- edge pass: softmax coeffs, coeff atomics, edge_prompt stream-out ----
__global__ __launch_bounds__(256) void k_edge(
    const int* __restrict__ ei, const float* __restrict__ p12,
    const float* __restrict__ edge_anchor,
    float* __restrict__ coeff, float* __restrict__ ep) {
  __shared__ float bs[256][NA];
  const int t = threadIdx.x;
  const int e = blockIdx.x * 256 + t;
  const int src = ei[e], dst = ei[NE + e];
  float4 q1 = *(const float4*)(p12 + (size_t)src * 16);
  float p14 = p12[(size_t)src * 16 + 4];
  float4 q2 = *(const float4*)(p12 + (size_t)dst * 16 + 8);
  float p24 = p12[(size_t)dst * 16 + 12];
  float l[NA] = {q1.x + q2.x, q1.y + q2.y, q1.z + q2.z, q1.w + q2.w, p14 + p24};
#pragma unroll
  for (int a = 0; a < NA; ++a) l[a] = l[a] >= 0.f ? l[a] : 0.01f * l[a];
  float m = fmaxf(fmaxf(fmaxf(l[0], l[1]), fmaxf(l[2], l[3])), l[4]);
  float s = 0.f;
#pragma unroll
  for (int a = 0; a < NA; ++a) { l[a] = expf(l[a] - m); s += l[a]; }
  float inv = 1.f / s;
#pragma unroll
  for (int a = 0; a < NA; ++a) {
    float b = l[a] * inv;
    bs[t][a] = b;
    atomicAdd(coeff + (size_t)src * NA + a, b);
    atomicAdd(coeff + (size_t)dst * NA + a, b);
  }
  __syncthreads();
  const int wid = t >> 6, lane = t & 63, d0 = lane << 1;
  float ea0[NA], ea1[NA];
#pragma unroll
  for (int a = 0; a < NA; ++a) {
    ea0[a] = edge_anchor[a * DIM + d0];
    ea1[a] = edge_anchor[a * DIM + d0 + 1];
  }
  const size_t ebase = (size_t)blockIdx.x * 256;
  for (int k = 0; k < 64; ++k) {
    const int el = (wid << 6) + k;
    float c0 = bs[el][0], c1 = bs[el][1], c2 = bs[el][2], c3 = bs[el][3],
          c4 = bs[el][4];
    vf2 v;
    v[0] = c0 * ea0[0] + c1 * ea0[1] + c2 * ea0[2] + c3 * ea0[3] + c4 * ea0[4];
    v[1] = c0 * ea1[0] + c1 * ea1[1] + c2 * ea1[2] + c3 * ea1[3] + c4 * ea1[4];
    __builtin_nontemporal_store(v, (vf2*)(ep + (ebase + el) * DIM + d0));
  }
}

// ---- ODE: ev in LDS across all 5 steps; agg_proj reconstructed from coeff@M ----
#define MATVEC(SRC, WMAT, ACC)                                       \
  _Pragma("unroll 2") for (int j = 0; j < DIM; j += 4) {             \
    float av[4][4];                                                  \
    *(float4*)&av[0][0] = *(const float4*)&SRC[ng4 + 0][j];          \
    *(float4*)&av[1][0] = *(const float4*)&SRC[ng4 + 1][j];          \
    *(float4*)&av[2][0] = *(const float4*)&SRC[ng4 + 2][j];          \
    *(float4*)&av[3][0] = *(const float4*)&SRC[ng4 + 3][j];          \
    _Pragma("unroll") for (int jj = 0; jj < 4; ++jj) {               \
      const float* wr = WMAT + (j + jj) * DIM + i0;                  \
      float4 w0 = *(const float4*)wr;                                \
      float4 w1 = *(const float4*)(wr + 4);                          \
      float wv[8] = {w0.x, w0.y, w0.z, w0.w, w1.x, w1.y, w1.z, w1.w};\
      _Pragma("unroll") for (int k = 0; k < 4; ++k)                  \
          _Pragma("unroll") for (int u = 0; u < 8; ++u)              \
              ACC[k][u] = fmaf(av[k][jj], wv[u], ACC[k][u]);         \
    }                                                                \
  }

__global__ __launch_bounds__(192) void k_ode(
    const float* __restrict__ coeff, const float* __restrict__ M,
    const float* __restrict__ W1aT, const float* __restrict__ W2T,
    const float* __restrict__ b1, const float* __restrict__ b2,
    float* __restrict__ ev) {
  __shared__ float evs[ODE_NB][132];
  __shared__ float hs[ODE_NB][132];
  const int t = threadIdx.x;
  const int ng = t >> 4, dg = t & 15;
  const int i0 = dg << 3;
  const int nbase = blockIdx.x * ODE_NB;
  const int ng4 = ng << 2;
  {
    const int r = t >> 2, c0 = (t & 3) << 5;
    const int n = nbase + r;
#pragma unroll
    for (int u = 0; u < 32; u += 4) {
      float4 v = make_float4(0.f, 0.f, 0.f, 0.f);
      if (n < NN) v = *(const float4*)(ev + (size_t)n * DIM + c0 + u);
      *(float4*)&evs[r][c0 + u] = v;
    }
  }
  float aggp[4][8];
  {
    float Mr[NA][8], b1r[8];
#pragma unroll
    for (int u = 0; u < 8; ++u) b1r[u] = b1[i0 + u];
#pragma unroll
    for (int a = 0; a < NA; ++a)
#pragma unroll
      for (int u = 0; u < 8; ++u) Mr[a][u] = M[a * DIM + i0 + u];
#pragma unroll
    for (int k = 0; k < 4; ++k) {
      const int n = nbase + ng4 + k;
      float c[NA];
#pragma unroll
      for (int a = 0; a < NA; ++a)
        c[a] = (n < NN) ? coeff[(size_t)n * NA + a] : 0.f;
#pragma unroll
      for (int u = 0; u < 8; ++u) {
        float s = b1r[u];
#pragma unroll
        for (int a = 0; a < NA; ++a) s = fmaf(c[a], Mr[a][u], s);
        aggp[k][u] = s;
      }
    }
  }
  float b2r[8];
#pragma unroll
  for (int u = 0; u < 8; ++u) b2r[u] = b2[i0 + u];
  __syncthreads();
  const float dt = 1.f / STEPS;
#pragma unroll 1
  for (int step = 0; step < STEPS; ++step) {
    float acc[4][8];
#pragma unroll
    for (int k = 0; k < 4; ++k)
#pragma unroll
      for (int u = 0; u < 8; ++u) acc[k][u] = aggp[k][u];
    MATVEC(evs, W1aT, acc)
#pragma unroll
    for (int k = 0; k < 4; ++k) {
      float4 h0 = make_float4(fmaxf(acc[k][0], 0.f), fmaxf(acc[k][1], 0.f),
                              fmaxf(acc[k][2], 0.f), fmaxf(acc[k][3], 0.f));
      float4 h1 = make_float4(fmaxf(acc[k][4], 0.f), fmaxf(acc[k][5], 0.f),
                              fmaxf(acc[k][6], 0.f), fmaxf(acc[k][7], 0.f));
      *(float4*)&hs[ng4 + k][i0] = h0;
      *(float4*)&hs[ng4 + k][i0 + 4] = h1;
    }
    __syncthreads();
    float acc2[4][8];
#pragma unroll
    for (int k = 0; k < 4; ++k)
#pragma unroll
      for (int u = 0; u < 8; ++u) acc2[k][u] = 0.f;
    MATVEC(hs, W2T, acc2)
#pragma unroll
    for (int k = 0; k < 4; ++k) {
      float4 e0 = *(float4*)&evs[ng4 + k][i0];
      float4 e1 = *(float4*)&evs[ng4 + k][i0 + 4];
      e0.x = fmaf(dt, acc2[k][0] + b2r[0], e0.x);
      e0.y = fmaf(dt, acc2[k][1] + b2r[1], e0.y);
      e0.z = fmaf(dt, acc2[k][2] + b2r[2], e0.z);
      e0.w = fmaf(dt, acc2[k][3] + b2r[3], e0.w);
      e1.x = fmaf(dt, acc2[k][4] + b2r[4], e1.x);
      e1.y = fmaf(dt, acc2[k][5] + b2r[5], e1.y);
      e1.z = fmaf(dt, acc2[k][6] + b2r[6], e1.z);
      e1.w = fmaf(dt, acc2[k][7] + b2r[7], e1.w);
      *(float4*)&evs[ng4 + k][i0] = e0;
      *(float4*)&evs[ng4 + k][i0 + 4] = e1;
    }
    __syncthreads();
  }
  {
    const int r = t >> 2, c0 = (t & 3) << 5;
    const int n = nbase + r;
    if (n < NN) {
#pragma unroll
      for (int u = 0; u < 32; u += 4)
        *(float4*)(ev + (size_t)n * DIM + c0 + u) = *(float4*)&evs[r][c0 + u];
    }
  }
}

extern "C" void kernel_launch(void* const* d_in, const int* in_sizes, int n_in,
                              void* d_out, int out_size, void* d_ws,
                              size_t ws_size, hipStream_t stream) {
  const float* x = (const float*)d_in[0];
  const int* ei = (const int*)d_in[1];
  const float* node_anchor = (const float*)d_in[2];
  const float* W_att = (const float*)d_in[3];
  const float* b_att = (const float*)d_in[4];
  const float* edge_anchor = (const float*)d_in[5];
  const float* W_edge = (const float*)d_in[6];
  const float* b_edge = (const float*)d_in[7];
  const float* W1 = (const float*)d_in[8];
  const float* b1 = (const float*)d_in[9];
  const float* W2 = (const float*)d_in[10];
  const float* b2 = (const float*)d_in[11];

  float* out = (float*)d_out;
  float* ev = out;                       // N*DIM (node_x staged here, then final ev)
  float* ep = out + (size_t)NN * DIM;    // E*DIM edge_prompt

  char* ws = (char*)d_ws;
  float* p12 = (float*)(ws);             // N*16 floats (p1[0..4] @ +0, p2[0..4] @ +8)
  float* coeff = (float*)(ws + 6400000); // N*5 floats
  float* Mm = (float*)(ws + 8400000);    // 5*128 floats
  float* W1aT = (float*)(ws + 8402560);  // 128*128
  float* W2T = (float*)(ws + 8468096);   // 128*128

  hipMemsetAsync(coeff, 0, (size_t)NN * NA * sizeof(float), stream);
  k_prep<<<DIM + NA, DIM, 0, stream>>>(W1, W2, edge_anchor, W1aT, W2T, Mm);
  k_node<<<2048, 256, 0, stream>>>(x, W_att, b_att, node_anchor, W_edge, b_edge,
                                   ev, p12);
  k_edge<<<NE / 256, 256, 0, stream>>>(ei, p12, edge_anchor, coeff, ep);
  k_ode<<<(NN + ODE_NB - 1) / ODE_NB, 192, 0, stream>>>(coeff, Mm, W1aT, W2T,
                                                        b1, b2, ev);
}

// Round 3
// 1241.104 us; speedup vs baseline: 1.2066x; 1.2066x over previous
//
#include <hip/hip_runtime.h>

#define NN 100000
#define NE 1600000
#define DIM 128
#define NA 5
#define STEPS 5
#define ODE_NB 48

// fixed-point packing for coeff atomics
#define CSCALE 1048576.0f            // 2^20
#define CINV   9.5367431640625e-07f  // 2^-20

typedef float vf2 __attribute__((ext_vector_type(2)));

__device__ __forceinline__ float wsum(float v) {
#pragma unroll
  for (int off = 32; off > 0; off >>= 1) v += __shfl_xor(v, off, 64);
  return v;
}

// ---- prep: transpose W1a, W2; M = edge_anchor @ W1b.T ----
__global__ __launch_bounds__(128) void k_prep(
    const float* __restrict__ W1, const float* __restrict__ W2,
    const float* __restrict__ edge_anchor,
    float* __restrict__ W1aT, float* __restrict__ W2T, float* __restrict__ M) {
  const int i = threadIdx.x;
  const int b = blockIdx.x;
  if (b < DIM) {
    W1aT[b * DIM + i] = W1[i * 2 * DIM + b];
    W2T[b * DIM + i] = W2[i * DIM + b];
  } else {
    const int a = b - DIM;
    float s = 0.f;
    for (int j = 0; j < DIM; ++j)
      s = fmaf(edge_anchor[a * DIM + j], W1[i * 2 * DIM + DIM + j], s);
    M[a * DIM + i] = s;
  }
}

// ---- node pre-pass: att softmax + node_x, and p1/p2 edge projections ----
// p12 layout per node (stride 12 floats): [0..4]=p1, [5]=pad, [6..10]=p2, [11]=pad
__global__ __launch_bounds__(256) void k_node(
    const float* __restrict__ x, const float* __restrict__ W_att,
    const float* __restrict__ b_att, const float* __restrict__ node_anchor,
    const float* __restrict__ W_edge, const float* __restrict__ b_edge,
    float* __restrict__ node_x, float* __restrict__ p12) {
  const int wid = threadIdx.x >> 6, lane = threadIdx.x & 63;
  const int d0 = lane << 1;
  float wa0[NA], wa1[NA], we10[NA], we11[NA], we20[NA], we21[NA];
  float na0[NA], na1[NA], ba[NA], be[NA];
#pragma unroll
  for (int a = 0; a < NA; ++a) {
    wa0[a] = W_att[a * DIM + d0];
    wa1[a] = W_att[a * DIM + d0 + 1];
    we10[a] = W_edge[a * 2 * DIM + d0];
    we11[a] = W_edge[a * 2 * DIM + d0 + 1];
    we20[a] = W_edge[a * 2 * DIM + DIM + d0];
    we21[a] = W_edge[a * 2 * DIM + DIM + d0 + 1];
    na0[a] = node_anchor[a * DIM + d0];
    na1[a] = node_anchor[a * DIM + d0 + 1];
    ba[a] = b_att[a];
    be[a] = b_edge[a];
  }
  const int stride = gridDim.x << 2;
  for (int n = (blockIdx.x << 2) + wid; n < NN; n += stride) {
    float2 xv = *(const float2*)(x + (size_t)n * DIM + d0);
    float att[NA], p1[NA], p2[NA];
#pragma unroll
    for (int a = 0; a < NA; ++a) {
      att[a] = wsum(xv.x * wa0[a] + xv.y * wa1[a]) + ba[a];
      p1[a] = wsum(xv.x * we10[a] + xv.y * we11[a]) + be[a];  // fold b_edge
      p2[a] = wsum(xv.x * we20[a] + xv.y * we21[a]);
    }
    float m = fmaxf(fmaxf(fmaxf(att[0], att[1]), fmaxf(att[2], att[3])), att[4]);
    float s = 0.f;
#pragma unroll
    for (int a = 0; a < NA; ++a) { att[a] = expf(att[a] - m); s += att[a]; }
    float inv = 1.f / s;
    float2 nx = xv;
#pragma unroll
    for (int a = 0; a < NA; ++a) {
      float w = att[a] * inv;
      nx.x = fmaf(w, na0[a], nx.x);
      nx.y = fmaf(w, na1[a], nx.y);
    }
    *(float2*)(node_x + (size_t)n * DIM + d0) = nx;
    if (lane < NA) {
      float v1 = p1[0], v2 = p2[0];
#pragma unroll
      for (int a = 1; a < NA; ++a)
        if (lane == a) { v1 = p1[a]; v2 = p2[a]; }
      p12[(size_t)n * 12 + lane] = v1;
      p12[(size_t)n * 12 + 6 + lane] = v2;
    }
  }
}

__device__ __forceinline__ void edge_b(const float* __restrict__ p12, int src,
                                       int dst, float* __restrict__ b) {
  float4 q1 = *(const float4*)(p12 + (size_t)src * 12);
  float p14 = p12[(size_t)src * 12 + 4];
  float2 r0 = *(const float2*)(p12 + (size_t)dst * 12 + 6);
  float2 r1 = *(const float2*)(p12 + (size_t)dst * 12 + 8);
  float p24 = p12[(size_t)dst * 12 + 10];
  float l[NA] = {q1.x + r0.x, q1.y + r0.y, q1.z + r1.x, q1.w + r1.y,
                 p14 + p24};
#pragma unroll
  for (int a = 0; a < NA; ++a) l[a] = l[a] >= 0.f ? l[a] : 0.01f * l[a];
  float m = fmaxf(fmaxf(fmaxf(l[0], l[1]), fmaxf(l[2], l[3])), l[4]);
  float s = 0.f;
#pragma unroll
  for (int a = 0; a < NA; ++a) { l[a] = expf(l[a] - m); s += l[a]; }
  float inv = 1.f / s;
#pragma unroll
  for (int a = 0; a < NA; ++a) b[a] = l[a] * inv;
}

// ---- coeff pass: pure atomics, fixed-point packed u64 (3 per endpoint) ----
__global__ __launch_bounds__(256) void k_coeff(
    const int* __restrict__ ei, const float* __restrict__ p12,
    unsigned long long* __restrict__ coeffp) {
  const int e = blockIdx.x * 256 + threadIdx.x;
  const int src = ei[e], dst = ei[NE + e];
  float b[NA];
  edge_b(p12, src, dst, b);
  unsigned q[NA];
#pragma unroll
  for (int a = 0; a < NA; ++a) q[a] = (unsigned)fmaf(b[a], CSCALE, 0.5f);
  unsigned long long p01 = (unsigned long long)q[0] |
                           ((unsigned long long)q[1] << 32);
  unsigned long long p23 = (unsigned long long)q[2] |
                           ((unsigned long long)q[3] << 32);
  unsigned long long p4 = (unsigned long long)q[4];
  atomicAdd(coeffp + (size_t)src * 3 + 0, p01);
  atomicAdd(coeffp + (size_t)src * 3 + 1, p23);
  atomicAdd(coeffp + (size_t)src * 3 + 2, p4);
  atomicAdd(coeffp + (size_t)dst * 3 + 0, p01);
  atomicAdd(coeffp + (size_t)dst * 3 + 1, p23);
  atomicAdd(coeffp + (size_t)dst * 3 + 2, p4);
}

// ---- ep pass: edge_prompt stream-out, no atomics, no __syncthreads ----
__global__ __launch_bounds__(256) void k_ep(
    const int* __restrict__ ei, const float* __restrict__ p12,
    const float* __restrict__ edge_anchor, float* __restrict__ ep) {
  __shared__ float bs[4][64][8];
  const int t = threadIdx.x;
  const int w = t >> 6, lane = t & 63, d0 = lane << 1;
  const int e = blockIdx.x * 256 + t;
  {
    float b[NA];
    edge_b(p12, ei[e], ei[NE + e], b);
    // wave-private LDS slice: same-wave DS ops are in-order, no barrier needed
    *(float4*)&bs[w][lane][0] = make_float4(b[0], b[1], b[2], b[3]);
    bs[w][lane][4] = b[4];
  }
  float ea0[NA], ea1[NA];
#pragma unroll
  for (int a = 0; a < NA; ++a) {
    ea0[a] = edge_anchor[a * DIM + d0];
    ea1[a] = edge_anchor[a * DIM + d0 + 1];
  }
  const size_t ebase = (size_t)blockIdx.x * 256 + ((size_t)w << 6);
#pragma unroll 2
  for (int k = 0; k < 64; ++k) {
    float4 c = *(const float4*)&bs[w][k][0];  // broadcast read
    float c4 = bs[w][k][4];
    vf2 v;
    v[0] = c.x * ea0[0] + c.y * ea0[1] + c.z * ea0[2] + c.w * ea0[3] +
           c4 * ea0[4];
    v[1] = c.x * ea1[0] + c.y * ea1[1] + c.z * ea1[2] + c.w * ea1[3] +
           c4 * ea1[4];
    __builtin_nontemporal_store(v, (vf2*)(ep + (ebase + k) * DIM + d0));
  }
}

// ---- ODE: ev in LDS across all 5 steps; agg_proj from unpacked coeff @ M ----
#define MATVEC(SRC, WMAT, ACC)                                       \
  _Pragma("unroll 2") for (int j = 0; j < DIM; j += 4) {             \
    float av[4][4];                                                  \
    *(float4*)&av[0][0] = *(const float4*)&SRC[ng4 + 0][j];          \
    *(float4*)&av[1][0] = *(const float4*)&SRC[ng4 + 1][j];          \
    *(float4*)&av[2][0] = *(const float4*)&SRC[ng4 + 2][j];          \
    *(float4*)&av[3][0] = *(const float4*)&SRC[ng4 + 3][j];          \
    _Pragma("unroll") for (int jj = 0; jj < 4; ++jj) {               \
      const float* wr = WMAT + (j + jj) * DIM + i0;                  \
      float4 w0 = *(const float4*)wr;                                \
      float4 w1 = *(const float4*)(wr + 4);                          \
      float wv[8] = {w0.x, w0.y, w0.z, w0.w, w1.x, w1.y, w1.z, w1.w};\
      _Pragma("unroll") for (int k = 0; k < 4; ++k)                  \
          _Pragma("unroll") for (int u = 0; u < 8; ++u)              \
              ACC[k][u] = fmaf(av[k][jj], wv[u], ACC[k][u]);         \
    }                                                                \
  }

__global__ __launch_bounds__(192) void k_ode(
    const unsigned long long* __restrict__ coeffp, const float* __restrict__ M,
    const float* __restrict__ W1aT, const float* __restrict__ W2T,
    const float* __restrict__ b1, const float* __restrict__ b2,
    float* __restrict__ ev) {
  __shared__ float evs[ODE_NB][132];
  __shared__ float hs[ODE_NB][132];
  const int t = threadIdx.x;
  const int ng = t >> 4, dg = t & 15;
  const int i0 = dg << 3;
  const int nbase = blockIdx.x * ODE_NB;
  const int ng4 = ng << 2;
  {
    const int r = t >> 2, c0 = (t & 3) << 5;
    const int n = nbase + r;
#pragma unroll
    for (int u = 0; u < 32; u += 4) {
      float4 v = make_float4(0.f, 0.f, 0.f, 0.f);
      if (n < NN) v = *(const float4*)(ev + (size_t)n * DIM + c0 + u);
      *(float4*)&evs[r][c0 + u] = v;
    }
  }
  float aggp[4][8];
  {
    float Mr[NA][8], b1r[8];
#pragma unroll
    for (int u = 0; u < 8; ++u) b1r[u] = b1[i0 + u];
#pragma unroll
    for (int a = 0; a < NA; ++a)
#pragma unroll
      for (int u = 0; u < 8; ++u) Mr[a][u] = M[a * DIM + i0 + u];
#pragma unroll
    for (int k = 0; k < 4; ++k) {
      const int n = nbase + ng4 + k;
      float c[NA];
#pragma unroll
      for (int a = 0; a < NA; ++a) c[a] = 0.f;
      if (n < NN) {
        unsigned long long v0 = coeffp[(size_t)n * 3 + 0];
        unsigned long long v1 = coeffp[(size_t)n * 3 + 1];
        unsigned long long v2 = coeffp[(size_t)n * 3 + 2];
        c[0] = (float)(unsigned)v0 * CINV;
        c[1] = (float)(unsigned)(v0 >> 32) * CINV;
        c[2] = (float)(unsigned)v1 * CINV;
        c[3] = (float)(unsigned)(v1 >> 32) * CINV;
        c[4] = (float)(unsigned)v2 * CINV;
      }
#pragma unroll
      for (int u = 0; u < 8; ++u) {
        float s = b1r[u];
#pragma unroll
        for (int a = 0; a < NA; ++a) s = fmaf(c[a], Mr[a][u], s);
        aggp[k][u] = s;
      }
    }
  }
  float b2r[8];
#pragma unroll
  for (int u = 0; u < 8; ++u) b2r[u] = b2[i0 + u];
  __syncthreads();
  const float dt = 1.f / STEPS;
#pragma unroll 1
  for (int step = 0; step < STEPS; ++step) {
    float acc[4][8];
#pragma unroll
    for (int k = 0; k < 4; ++k)
#pragma unroll
      for (int u = 0; u < 8; ++u) acc[k][u] = aggp[k][u];
    MATVEC(evs, W1aT, acc)
#pragma unroll
    for (int k = 0; k < 4; ++k) {
      float4 h0 = make_float4(fmaxf(acc[k][0], 0.f), fmaxf(acc[k][1], 0.f),
                              fmaxf(acc[k][2], 0.f), fmaxf(acc[k][3], 0.f));
      float4 h1 = make_float4(fmaxf(acc[k][4], 0.f), fmaxf(acc[k][5], 0.f),
                              fmaxf(acc[k][6], 0.f), fmaxf(acc[k][7], 0.f));
      *(float4*)&hs[ng4 + k][i0] = h0;
      *(float4*)&hs[ng4 + k][i0 + 4] = h1;
    }
    __syncthreads();
    float acc2[4][8];
#pragma unroll
    for (int k = 0; k < 4; ++k)
#pragma unroll
      for (int u = 0; u < 8; ++u) acc2[k][u] = 0.f;
    MATVEC(hs, W2T, acc2)
#pragma unroll
    for (int k = 0; k < 4; ++k) {
      float4 e0 = *(float4*)&evs[ng4 + k][i0];
      float4 e1 = *(float4*)&evs[ng4 + k][i0 + 4];
      e0.x = fmaf(dt, acc2[k][0] + b2r[0], e0.x);
      e0.y = fmaf(dt, acc2[k][1] + b2r[1], e0.y);
      e0.z = fmaf(dt, acc2[k][2] + b2r[2], e0.z);
      e0.w = fmaf(dt, acc2[k][3] + b2r[3], e0.w);
      e1.x = fmaf(dt, acc2[k][4] + b2r[4], e1.x);
      e1.y = fmaf(dt, acc2[k][5] + b2r[5], e1.y);
      e1.z = fmaf(dt, acc2[k][6] + b2r[6], e1.z);
      e1.w = fmaf(dt, acc2[k][7] + b2r[7], e1.w);
      *(float4*)&evs[ng4 + k][i0] = e0;
      *(float4*)&evs[ng4 + k][i0 + 4] = e1;
    }
    __syncthreads();
  }
  {
    const int r = t >> 2, c0 = (t & 3) << 5;
    const int n = nbase + r;
    if (n < NN) {
#pragma unroll
      for (int u = 0; u < 32; u += 4)
        *(float4*)(ev + (size_t)n * DIM + c0 + u) = *(float4*)&evs[r][c0 + u];
    }
  }
}

extern "C" void kernel_launch(void* const* d_in, const int* in_sizes, int n_in,
                              void* d_out, int out_size, void* d_ws,
                              size_t ws_size, hipStream_t stream) {
  const float* x = (const float*)d_in[0];
  const int* ei = (const int*)d_in[1];
  const float* node_anchor = (const float*)d_in[2];
  const float* W_att = (const float*)d_in[3];
  const float* b_att = (const float*)d_in[4];
  const float* edge_anchor = (const float*)d_in[5];
  const float* W_edge = (const float*)d_in[6];
  const float* b_edge = (const float*)d_in[7];
  const float* W1 = (const float*)d_in[8];
  const float* b1 = (const float*)d_in[9];
  const float* W2 = (const float*)d_in[10];
  const float* b2 = (const float*)d_in[11];

  float* out = (float*)d_out;
  float* ev = out;                     // N*DIM (node_x staged here, then final ev)
  float* ep = out + (size_t)NN * DIM;  // E*DIM edge_prompt

  char* ws = (char*)d_ws;
  float* p12 = (float*)(ws);  // N*12 floats = 4.8 MB
  unsigned long long* coeffp =
      (unsigned long long*)(ws + 4800000);  // N*3 u64 = 2.4 MB
  float* Mm = (float*)(ws + 7200000);       // 5*128
  float* W1aT = (float*)(ws + 7202560);     // 128*128
  float* W2T = (float*)(ws + 7268096);      // 128*128  (ends at 7,333,632)

  hipMemsetAsync(coeffp, 0, (size_t)NN * 3 * sizeof(unsigned long long),
                 stream);
  k_prep<<<DIM + NA, DIM, 0, stream>>>(W1, W2, edge_anchor, W1aT, W2T, Mm);
  k_node<<<2048, 256, 0, stream>>>(x, W_att, b_att, node_anchor, W_edge, b_edge,
                                   ev, p12);
  k_coeff<<<NE / 256, 256, 0, stream>>>(ei, p12, coeffp);
  k_ep<<<NE / 256, 256, 0, stream>>>(ei, p12, edge_anchor, ep);
  k_ode<<<(NN + ODE_NB - 1) / ODE_NB, 192, 0, stream>>>(coeffp, Mm, W1aT, W2T,
                                                        b1, b2, ev);
}